// Round 6
// baseline (404.285 us; speedup 1.0000x reference)
//
#include <hip/hip_runtime.h>

#define C_IN 256
#define C_OUT 256
#define NH 4
#define HD 64
#define NEG_SLOPE 0.2f

typedef _Float16 half8 __attribute__((ext_vector_type(8)));
typedef _Float16 half4v __attribute__((ext_vector_type(4)));
typedef float floatx4 __attribute__((ext_vector_type(4)));

// ---------------------------------------------------------------------------
// K1: collapse (Wl,att_l)->Ws[:,0:4], (Wr,att_r)->Ws[:,4:8]; biases -> bs[8].
// ---------------------------------------------------------------------------
__global__ void make_eff_w(const float* __restrict__ Wl, const float* __restrict__ Wr,
                           const float* __restrict__ bl, const float* __restrict__ br,
                           const float* __restrict__ attl, const float* __restrict__ attr,
                           float* __restrict__ Ws, float* __restrict__ bs)
{
    int c = blockIdx.x;
    int t = threadIdx.x;          // t = h*64 + d
    int h = t >> 6, d = t & 63;
    float al = attl[t], ar = attr[t];
    float vl, vr;
    if (c < C_IN) { vl = Wl[c * C_OUT + t] * al; vr = Wr[c * C_OUT + t] * ar; }
    else          { vl = bl[t] * al;             vr = br[t] * ar; }
#pragma unroll
    for (int off = 32; off >= 1; off >>= 1) {
        vl += __shfl_xor(vl, off, 64);
        vr += __shfl_xor(vr, off, 64);
    }
    if (d == 0) {
        if (c < C_IN) { Ws[c * 8 + h] = vl; Ws[c * 8 + 4 + h] = vr; }
        else          { bs[h] = vl;         bs[4 + h] = vr; }
    }
}

// ---------------------------------------------------------------------------
// Transpose Wv (k-major fp32) -> WvT (n-major f16).
// ---------------------------------------------------------------------------
__global__ void transpose_w(const float* __restrict__ Wv, _Float16* __restrict__ WvT)
{
    int idx = blockIdx.x * 256 + threadIdx.x;
    int n = idx >> 8, k = idx & 255;
    WvT[n * 256 + k] = (_Float16)Wv[k * 256 + n];
}

// ---------------------------------------------------------------------------
// K2: s[n][0..7] = x[n] @ Ws + bs  (hlr). One wave per node.
// ---------------------------------------------------------------------------
__global__ __launch_bounds__(256) void node_scores(const float* __restrict__ x,
    const float* __restrict__ Ws, const float* __restrict__ bs,
    float* __restrict__ s, int N)
{
    int lane = threadIdx.x & 63, wid = threadIdx.x >> 6;
    float w[4][8];
#pragma unroll
    for (int i = 0; i < 4; ++i)
#pragma unroll
        for (int jq = 0; jq < 2; ++jq) {
            float4 v = *(const float4*)(Ws + (4 * lane + i) * 8 + jq * 4);
            w[i][jq * 4 + 0] = v.x; w[i][jq * 4 + 1] = v.y;
            w[i][jq * 4 + 2] = v.z; w[i][jq * 4 + 3] = v.w;
        }
    float b0[8];
#pragma unroll
    for (int j = 0; j < 8; ++j) b0[j] = bs[j];

    int wglob = blockIdx.x * 4 + wid;
    int nwaves = gridDim.x * 4;
    for (int n = wglob; n < N; n += nwaves) {
        float4 xv4 = *(const float4*)(x + (size_t)n * 256 + 4 * lane);
        float acc[8];
#pragma unroll
        for (int j = 0; j < 8; ++j)
            acc[j] = xv4.x * w[0][j] + xv4.y * w[1][j] + xv4.z * w[2][j] + xv4.w * w[3][j];
#pragma unroll
        for (int off = 32; off >= 1; off >>= 1)
#pragma unroll
            for (int j = 0; j < 8; ++j) acc[j] += __shfl_xor(acc[j], off, 64);
        if (lane == 0) {
            *(float4*)(s + (size_t)n * 8)     = make_float4(acc[0] + b0[0], acc[1] + b0[1], acc[2] + b0[2], acc[3] + b0[3]);
            *(float4*)(s + (size_t)n * 8 + 4) = make_float4(acc[4] + b0[4], acc[5] + b0[5], acc[6] + b0[6], acc[7] + b0[7]);
        }
    }
}

// ---------------------------------------------------------------------------
// GEMM: xv = f16(x) @ f16(Wv) + bv, output stored f16. 128x128 tile, BK=32.
// (Exact round-1/round-4 proven version, scalar As staging stores.)
// ---------------------------------------------------------------------------
__global__ __launch_bounds__(256) void gemm_xv(const float* __restrict__ x,
    const _Float16* __restrict__ WvT, const float* __restrict__ bv,
    _Float16* __restrict__ xv, int M)
{
    __shared__ __align__(16) _Float16 As[128][40];
    __shared__ __align__(16) _Float16 Bs[128][40];
    int tid = threadIdx.x;
    int wid = tid >> 6, lane = tid & 63;
    int quad = lane >> 4, r16 = lane & 15;
    int m0 = blockIdx.x * 128, n0 = blockIdx.y * 128;

    floatx4 acc[2][8];
#pragma unroll
    for (int i = 0; i < 2; ++i)
#pragma unroll
        for (int j = 0; j < 8; ++j) acc[i][j] = (floatx4){0.f, 0.f, 0.f, 0.f};

    int arow = tid >> 3, af4 = tid & 7;
    int brow = tid >> 2, bg  = tid & 3;

    for (int k0 = 0; k0 < 256; k0 += 32) {
#pragma unroll
        for (int p = 0; p < 4; ++p) {
            int rr = arow + p * 32;
            int gm = m0 + rr;
            float4 v = make_float4(0.f, 0.f, 0.f, 0.f);
            if (gm < M) v = *(const float4*)(x + (size_t)gm * 256 + k0 + af4 * 4);
            _Float16* dp = &As[rr][af4 * 4];
            dp[0] = (_Float16)v.x; dp[1] = (_Float16)v.y;
            dp[2] = (_Float16)v.z; dp[3] = (_Float16)v.w;
        }
#pragma unroll
        for (int p = 0; p < 2; ++p) {
            int nr = brow + p * 64;
            *(float4*)&Bs[nr][bg * 8] = *(const float4*)(WvT + (size_t)(n0 + nr) * 256 + k0 + bg * 8);
        }
        __syncthreads();
        half8 a[2], b[8];
#pragma unroll
        for (int rg = 0; rg < 2; ++rg)
            a[rg] = *(const half8*)&As[wid * 32 + rg * 16 + r16][quad * 8];
#pragma unroll
        for (int cg = 0; cg < 8; ++cg)
            b[cg] = *(const half8*)&Bs[cg * 16 + r16][quad * 8];
#pragma unroll
        for (int rg = 0; rg < 2; ++rg)
#pragma unroll
            for (int cg = 0; cg < 8; ++cg)
                acc[rg][cg] = __builtin_amdgcn_mfma_f32_16x16x32_f16(a[rg], b[cg], acc[rg][cg], 0, 0, 0);
        __syncthreads();
    }
#pragma unroll
    for (int rg = 0; rg < 2; ++rg) {
        int rbase = m0 + wid * 32 + rg * 16 + quad * 4;
#pragma unroll
        for (int cg = 0; cg < 8; ++cg) {
            int gcol = n0 + cg * 16 + r16;
            float bias = bv[gcol];
#pragma unroll
            for (int rr = 0; rr < 4; ++rr) {
                int grow = rbase + rr;
                if (grow < M)
                    xv[(size_t)grow * 256 + gcol] = (_Float16)(acc[rg][cg][rr] + bias);
            }
        }
    }
}

// ---------------------------------------------------------------------------
// CSR build.
// ---------------------------------------------------------------------------
__global__ void deg_kernel(const int* __restrict__ dst, int* __restrict__ deg, int E)
{
    int i = blockIdx.x * 256 + threadIdx.x;
    if (i < E) atomicAdd(&deg[dst[i]], 1);
}

__global__ void scan_part(const int* __restrict__ deg, int* __restrict__ partials,
                          int N, int chunk)
{
    __shared__ int sd[256];
    int b = blockIdx.x, t = threadIdx.x;
    int idx = b * chunk + t;
    int v = (t < chunk && idx < N) ? deg[idx] : 0;
    sd[t] = v; __syncthreads();
    for (int off = 128; off >= 1; off >>= 1) {
        if (t < off) sd[t] += sd[t + off];
        __syncthreads();
    }
    if (t == 0) partials[b] = sd[0];
}

__global__ void scan_partials(const int* __restrict__ partials, int* __restrict__ pscan)
{
    __shared__ int sd[256];
    int t = threadIdx.x;
    int v = partials[t];
    sd[t] = v; __syncthreads();
    for (int off = 1; off < 256; off <<= 1) {
        int x = (t >= off) ? sd[t - off] : 0;
        __syncthreads();
        sd[t] += x;
        __syncthreads();
    }
    pscan[t] = sd[t] - v;  // exclusive
}

__global__ void scan_final(const int* __restrict__ deg, const int* __restrict__ pscan,
                           int* __restrict__ offs, int N, int chunk)
{
    __shared__ int sd[256];
    int b = blockIdx.x, t = threadIdx.x;
    int idx = b * chunk + t;
    int v = (t < chunk && idx < N) ? deg[idx] : 0;
    sd[t] = v; __syncthreads();
    for (int off = 1; off < 256; off <<= 1) {
        int x = (t >= off) ? sd[t - off] : 0;
        __syncthreads();
        sd[t] += x;
        __syncthreads();
    }
    int incl = sd[t], excl = incl - v;
    int base = pscan[b];
    if (t < chunk && idx < N) offs[idx] = base + excl;
    if (idx == N - 1) offs[N] = base + incl;  // == E
}

__global__ void scatter_kernel(const int* __restrict__ src, const int* __restrict__ dst,
                               const int* __restrict__ offs, int* __restrict__ cursor,
                               int* __restrict__ csr_src, int E)
{
    int i = blockIdx.x * 256 + threadIdx.x;
    if (i < E) {
        int d = dst[i];
        int p = offs[d] + atomicAdd(&cursor[d], 1);
        csr_src[p] = src[i];
    }
}

// ---------------------------------------------------------------------------
// agg = (hlr + segsum(hlr[src] by dst)) / (1+deg). EIGHT threads per node,
// one channel each: grid 8x larger (1563 blocks vs 196), csr_src read is
// wave-broadcast (8 lanes same addr), s[p*8+c] reads of the 8 lanes form one
// coalesced 32B segment. Unroll x4 for independent loads. No cross-lane
// communication (each thread owns its channel end-to-end).
// ---------------------------------------------------------------------------
__global__ void agg_kernel(const float* __restrict__ s, const int* __restrict__ csr_src,
                           const int* __restrict__ offs, const int* __restrict__ deg,
                           float* __restrict__ aggl, float* __restrict__ aggr, int N)
{
    int gid = blockIdx.x * 256 + threadIdx.x;
    int n = gid >> 3, c = gid & 7;
    if (n >= N) return;
    int off = offs[n], dg = deg[n];
    float acc = s[(size_t)n * 8 + c];
    int i = 0;
    for (; i + 4 <= dg; i += 4) {
        int p0 = csr_src[off + i];
        int p1 = csr_src[off + i + 1];
        int p2 = csr_src[off + i + 2];
        int p3 = csr_src[off + i + 3];
        float v0 = s[(size_t)p0 * 8 + c];
        float v1 = s[(size_t)p1 * 8 + c];
        float v2 = s[(size_t)p2 * 8 + c];
        float v3 = s[(size_t)p3 * 8 + c];
        acc += (v0 + v1) + (v2 + v3);
    }
    for (; i < dg; ++i) acc += s[(size_t)csr_src[off + i] * 8 + c];
    acc *= 1.0f / (1.0f + (float)dg);
    if (c < 4) aggl[(size_t)n * 4 + c]     = acc;
    else       aggr[(size_t)n * 4 + c - 4] = acc;
}

// ---------------------------------------------------------------------------
// Fused softmax + value aggregation, single sweep (proven round-4 math,
// round-5 phased structure). __launch_bounds__(256,4) grants a 128-VGPR
// budget so the compiler can ACTUALLY keep the 16 xv + 16 aggl loads in
// flight (round 5's default budget clamped VGPRs to 56 and serialized the
// phases; round 4 measured only ~51% occupancy anyway, so 4 waves/SIMD
// sacrifices nothing).
// ---------------------------------------------------------------------------
__global__ __launch_bounds__(256, 4) void attn_out(const float* __restrict__ aggl,
    const float* __restrict__ aggr, const int* __restrict__ csr_src,
    const int* __restrict__ offs, const int* __restrict__ deg,
    const _Float16* __restrict__ xv, float* __restrict__ out, int N)
{
    int wid = threadIdx.x >> 6, lane = threadIdx.x & 63;
    int n = blockIdx.x * 4 + wid;
    if (n >= N) return;
    int h = lane >> 4, j16 = lane & 15;
    int off = offs[n], dg = deg[n];
    float ar = aggr[(size_t)n * 4 + h];

    float denom = 0.f, o0 = 0.f, o1 = 0.f, o2 = 0.f, o3 = 0.f;
    for (int i0 = 0; i0 < dg; i0 += 16) {
        int cs = (i0 + j16 < dg) ? csr_src[off + i0 + j16] : -1;
        int sidx[16];
#pragma unroll
        for (int j = 0; j < 16; ++j) sidx[j] = __shfl(cs, j, 64);

        half4v hv[16];
#pragma unroll
        for (int j = 0; j < 16; ++j) {
            int si = (sidx[j] >= 0) ? sidx[j] : 0;
            hv[j] = *(const half4v*)(xv + (size_t)si * 256 + lane * 4);
        }

        float wv[16];
#pragma unroll
        for (int j = 0; j < 16; ++j) {
            int si = (sidx[j] >= 0) ? sidx[j] : 0;
            float e = aggl[(size_t)si * 4 + h] + ar;
            e = (e > 0.f) ? e : NEG_SLOPE * e;
            wv[j] = (sidx[j] >= 0) ? __expf(e) : 0.f;
        }

#pragma unroll
        for (int j = 0; j < 16; ++j) {
            denom += wv[j];
            o0 += wv[j] * (float)hv[j][0];
            o1 += wv[j] * (float)hv[j][1];
            o2 += wv[j] * (float)hv[j][2];
            o3 += wv[j] * (float)hv[j][3];
        }
    }
    float inv = 1.0f / fmaxf(denom, 1e-16f);
    *(float4*)(out + (size_t)n * 256 + lane * 4) = make_float4(o0 * inv, o1 * inv, o2 * inv, o3 * inv);
}

// ---------------------------------------------------------------------------
extern "C" void kernel_launch(void* const* d_in, const int* in_sizes, int n_in,
                              void* d_out, int out_size, void* d_ws, size_t ws_size,
                              hipStream_t stream)
{
    const float* x    = (const float*)d_in[0];
    const int*   src  = (const int*)d_in[1];
    const int*   dst  = (const int*)d_in[2];
    const float* Wl   = (const float*)d_in[3];
    const float* bl   = (const float*)d_in[4];
    const float* Wr   = (const float*)d_in[5];
    const float* br   = (const float*)d_in[6];
    const float* Wv   = (const float*)d_in[7];
    const float* bv   = (const float*)d_in[8];
    const float* attl = (const float*)d_in[9];
    const float* attr = (const float*)d_in[10];
    float* out = (float*)d_out;

    int N = in_sizes[0] / C_IN;
    int E = in_sizes[1];

    char* p = (char*)d_ws;
    auto alloc = [&](size_t bytes) -> void* {
        uintptr_t q = (uintptr_t)p;
        q = (q + 255) & ~(uintptr_t)255;
        p = (char*)(q + bytes);
        return (void*)q;
    };
    // Exact round-1/round-4 workspace layout (~32.8 MB, proven to fit).
    float* Ws     = (float*)alloc((size_t)C_IN * 8 * sizeof(float));
    float* bs     = (float*)alloc(8 * sizeof(float));
    float* s      = (float*)alloc((size_t)N * 8 * sizeof(float));
    float* aggl   = (float*)alloc((size_t)N * 4 * sizeof(float));
    float* aggr   = (float*)alloc((size_t)N * 4 * sizeof(float));
    int* deg      = (int*)alloc((size_t)N * sizeof(int));
    int* offs     = (int*)alloc((size_t)(N + 1) * sizeof(int));
    int* cursor   = (int*)alloc((size_t)N * sizeof(int));
    int* partials = (int*)alloc(256 * sizeof(int));
    int* pscan    = (int*)alloc(256 * sizeof(int));
    int* csr_src  = (int*)alloc((size_t)E * sizeof(int));
    _Float16* WvT = (_Float16*)alloc((size_t)C_IN * C_OUT * sizeof(_Float16));
    _Float16* xv  = (_Float16*)alloc((size_t)N * C_OUT * sizeof(_Float16));

    hipMemsetAsync(deg, 0, (size_t)N * sizeof(int), stream);
    hipMemsetAsync(cursor, 0, (size_t)N * sizeof(int), stream);

    make_eff_w<<<C_IN + 1, 256, 0, stream>>>(Wl, Wr, bl, br, attl, attr, Ws, bs);
    transpose_w<<<(C_IN * C_OUT) / 256, 256, 0, stream>>>(Wv, WvT);
    node_scores<<<768, 256, 0, stream>>>(x, Ws, bs, s, N);
    gemm_xv<<<dim3((N + 127) / 128, C_OUT / 128), 256, 0, stream>>>(x, WvT, bv, xv, N);
    deg_kernel<<<(E + 255) / 256, 256, 0, stream>>>(dst, deg, E);
    int chunk = (N + 255) / 256;
    scan_part<<<256, 256, 0, stream>>>(deg, partials, N, chunk);
    scan_partials<<<1, 256, 0, stream>>>(partials, pscan);
    scan_final<<<256, 256, 0, stream>>>(deg, pscan, offs, N, chunk);
    scatter_kernel<<<(E + 255) / 256, 256, 0, stream>>>(src, dst, offs, cursor, csr_src, E);
    agg_kernel<<<(N * 8 + 255) / 256, 256, 0, stream>>>(s, csr_src, offs, deg, aggl, aggr, N);
    attn_out<<<(N + 3) / 4, 256, 0, stream>>>(aggl, aggr, csr_src, offs, deg, xv, out, N);
}

// Round 7
// 352.126 us; speedup vs baseline: 1.1481x; 1.1481x over previous
//
#include <hip/hip_runtime.h>

#define C_IN 256
#define C_OUT 256
#define NH 4
#define HD 64
#define NEG_SLOPE 0.2f

typedef _Float16 half8 __attribute__((ext_vector_type(8)));
typedef _Float16 half4v __attribute__((ext_vector_type(4)));
typedef float floatx4 __attribute__((ext_vector_type(4)));

// ---------------------------------------------------------------------------
// K1: collapse (Wl,att_l)->Ws[:,0:4], (Wr,att_r)->Ws[:,4:8]; biases -> bs[8].
// ---------------------------------------------------------------------------
__global__ void make_eff_w(const float* __restrict__ Wl, const float* __restrict__ Wr,
                           const float* __restrict__ bl, const float* __restrict__ br,
                           const float* __restrict__ attl, const float* __restrict__ attr,
                           float* __restrict__ Ws, float* __restrict__ bs)
{
    int c = blockIdx.x;
    int t = threadIdx.x;          // t = h*64 + d
    int h = t >> 6, d = t & 63;
    float al = attl[t], ar = attr[t];
    float vl, vr;
    if (c < C_IN) { vl = Wl[c * C_OUT + t] * al; vr = Wr[c * C_OUT + t] * ar; }
    else          { vl = bl[t] * al;             vr = br[t] * ar; }
#pragma unroll
    for (int off = 32; off >= 1; off >>= 1) {
        vl += __shfl_xor(vl, off, 64);
        vr += __shfl_xor(vr, off, 64);
    }
    if (d == 0) {
        if (c < C_IN) { Ws[c * 8 + h] = vl; Ws[c * 8 + 4 + h] = vr; }
        else          { bs[h] = vl;         bs[4 + h] = vr; }
    }
}

// ---------------------------------------------------------------------------
// Transpose Wv (k-major fp32) -> WvT (n-major f16).
// ---------------------------------------------------------------------------
__global__ void transpose_w(const float* __restrict__ Wv, _Float16* __restrict__ WvT)
{
    int idx = blockIdx.x * 256 + threadIdx.x;
    int n = idx >> 8, k = idx & 255;
    WvT[n * 256 + k] = (_Float16)Wv[k * 256 + n];
}

// ---------------------------------------------------------------------------
// K2: s[n][0..7] = x[n] @ Ws + bs  (hlr). One wave per node.
// ---------------------------------------------------------------------------
__global__ __launch_bounds__(256) void node_scores(const float* __restrict__ x,
    const float* __restrict__ Ws, const float* __restrict__ bs,
    float* __restrict__ s, int N)
{
    int lane = threadIdx.x & 63, wid = threadIdx.x >> 6;
    float w[4][8];
#pragma unroll
    for (int i = 0; i < 4; ++i)
#pragma unroll
        for (int jq = 0; jq < 2; ++jq) {
            float4 v = *(const float4*)(Ws + (4 * lane + i) * 8 + jq * 4);
            w[i][jq * 4 + 0] = v.x; w[i][jq * 4 + 1] = v.y;
            w[i][jq * 4 + 2] = v.z; w[i][jq * 4 + 3] = v.w;
        }
    float b0[8];
#pragma unroll
    for (int j = 0; j < 8; ++j) b0[j] = bs[j];

    int wglob = blockIdx.x * 4 + wid;
    int nwaves = gridDim.x * 4;
    for (int n = wglob; n < N; n += nwaves) {
        float4 xv4 = *(const float4*)(x + (size_t)n * 256 + 4 * lane);
        float acc[8];
#pragma unroll
        for (int j = 0; j < 8; ++j)
            acc[j] = xv4.x * w[0][j] + xv4.y * w[1][j] + xv4.z * w[2][j] + xv4.w * w[3][j];
#pragma unroll
        for (int off = 32; off >= 1; off >>= 1)
#pragma unroll
            for (int j = 0; j < 8; ++j) acc[j] += __shfl_xor(acc[j], off, 64);
        if (lane == 0) {
            *(float4*)(s + (size_t)n * 8)     = make_float4(acc[0] + b0[0], acc[1] + b0[1], acc[2] + b0[2], acc[3] + b0[3]);
            *(float4*)(s + (size_t)n * 8 + 4) = make_float4(acc[4] + b0[4], acc[5] + b0[5], acc[6] + b0[6], acc[7] + b0[7]);
        }
    }
}

// ---------------------------------------------------------------------------
// GEMM: xv = f16(x) @ f16(Wv) + bv, output stored f16. 128x128 tile, BK=32.
// (Exact round-1/round-4 proven version, scalar As staging stores.)
// ---------------------------------------------------------------------------
__global__ __launch_bounds__(256) void gemm_xv(const float* __restrict__ x,
    const _Float16* __restrict__ WvT, const float* __restrict__ bv,
    _Float16* __restrict__ xv, int M)
{
    __shared__ __align__(16) _Float16 As[128][40];
    __shared__ __align__(16) _Float16 Bs[128][40];
    int tid = threadIdx.x;
    int wid = tid >> 6, lane = tid & 63;
    int quad = lane >> 4, r16 = lane & 15;
    int m0 = blockIdx.x * 128, n0 = blockIdx.y * 128;

    floatx4 acc[2][8];
#pragma unroll
    for (int i = 0; i < 2; ++i)
#pragma unroll
        for (int j = 0; j < 8; ++j) acc[i][j] = (floatx4){0.f, 0.f, 0.f, 0.f};

    int arow = tid >> 3, af4 = tid & 7;
    int brow = tid >> 2, bg  = tid & 3;

    for (int k0 = 0; k0 < 256; k0 += 32) {
#pragma unroll
        for (int p = 0; p < 4; ++p) {
            int rr = arow + p * 32;
            int gm = m0 + rr;
            float4 v = make_float4(0.f, 0.f, 0.f, 0.f);
            if (gm < M) v = *(const float4*)(x + (size_t)gm * 256 + k0 + af4 * 4);
            _Float16* dp = &As[rr][af4 * 4];
            dp[0] = (_Float16)v.x; dp[1] = (_Float16)v.y;
            dp[2] = (_Float16)v.z; dp[3] = (_Float16)v.w;
        }
#pragma unroll
        for (int p = 0; p < 2; ++p) {
            int nr = brow + p * 64;
            *(float4*)&Bs[nr][bg * 8] = *(const float4*)(WvT + (size_t)(n0 + nr) * 256 + k0 + bg * 8);
        }
        __syncthreads();
        half8 a[2], b[8];
#pragma unroll
        for (int rg = 0; rg < 2; ++rg)
            a[rg] = *(const half8*)&As[wid * 32 + rg * 16 + r16][quad * 8];
#pragma unroll
        for (int cg = 0; cg < 8; ++cg)
            b[cg] = *(const half8*)&Bs[cg * 16 + r16][quad * 8];
#pragma unroll
        for (int rg = 0; rg < 2; ++rg)
#pragma unroll
            for (int cg = 0; cg < 8; ++cg)
                acc[rg][cg] = __builtin_amdgcn_mfma_f32_16x16x32_f16(a[rg], b[cg], acc[rg][cg], 0, 0, 0);
        __syncthreads();
    }
#pragma unroll
    for (int rg = 0; rg < 2; ++rg) {
        int rbase = m0 + wid * 32 + rg * 16 + quad * 4;
#pragma unroll
        for (int cg = 0; cg < 8; ++cg) {
            int gcol = n0 + cg * 16 + r16;
            float bias = bv[gcol];
#pragma unroll
            for (int rr = 0; rr < 4; ++rr) {
                int grow = rbase + rr;
                if (grow < M)
                    xv[(size_t)grow * 256 + gcol] = (_Float16)(acc[rg][cg][rr] + bias);
            }
        }
    }
}

// ---------------------------------------------------------------------------
// CSR build.
// ---------------------------------------------------------------------------
__global__ void deg_kernel(const int* __restrict__ dst, int* __restrict__ deg, int E)
{
    int i = blockIdx.x * 256 + threadIdx.x;
    if (i < E) atomicAdd(&deg[dst[i]], 1);
}

__global__ void scan_part(const int* __restrict__ deg, int* __restrict__ partials,
                          int N, int chunk)
{
    __shared__ int sd[256];
    int b = blockIdx.x, t = threadIdx.x;
    int idx = b * chunk + t;
    int v = (t < chunk && idx < N) ? deg[idx] : 0;
    sd[t] = v; __syncthreads();
    for (int off = 128; off >= 1; off >>= 1) {
        if (t < off) sd[t] += sd[t + off];
        __syncthreads();
    }
    if (t == 0) partials[b] = sd[0];
}

__global__ void scan_partials(const int* __restrict__ partials, int* __restrict__ pscan)
{
    __shared__ int sd[256];
    int t = threadIdx.x;
    int v = partials[t];
    sd[t] = v; __syncthreads();
    for (int off = 1; off < 256; off <<= 1) {
        int x = (t >= off) ? sd[t - off] : 0;
        __syncthreads();
        sd[t] += x;
        __syncthreads();
    }
    pscan[t] = sd[t] - v;  // exclusive
}

__global__ void scan_final(const int* __restrict__ deg, const int* __restrict__ pscan,
                           int* __restrict__ offs, int N, int chunk)
{
    __shared__ int sd[256];
    int b = blockIdx.x, t = threadIdx.x;
    int idx = b * chunk + t;
    int v = (t < chunk && idx < N) ? deg[idx] : 0;
    sd[t] = v; __syncthreads();
    for (int off = 1; off < 256; off <<= 1) {
        int x = (t >= off) ? sd[t - off] : 0;
        __syncthreads();
        sd[t] += x;
        __syncthreads();
    }
    int incl = sd[t], excl = incl - v;
    int base = pscan[b];
    if (t < chunk && idx < N) offs[idx] = base + excl;
    if (idx == N - 1) offs[N] = base + incl;  // == E
}

__global__ void scatter_kernel(const int* __restrict__ src, const int* __restrict__ dst,
                               const int* __restrict__ offs, int* __restrict__ cursor,
                               int* __restrict__ csr_src, int E)
{
    int i = blockIdx.x * 256 + threadIdx.x;
    if (i < E) {
        int d = dst[i];
        int p = offs[d] + atomicAdd(&cursor[d], 1);
        csr_src[p] = src[i];
    }
}

// ---------------------------------------------------------------------------
// agg = (hlr + segsum(hlr[src] by dst)) / (1+deg). EIGHT threads per node,
// one channel each (proven round-6 version).
// ---------------------------------------------------------------------------
__global__ void agg_kernel(const float* __restrict__ s, const int* __restrict__ csr_src,
                           const int* __restrict__ offs, const int* __restrict__ deg,
                           float* __restrict__ aggl, float* __restrict__ aggr, int N)
{
    int gid = blockIdx.x * 256 + threadIdx.x;
    int n = gid >> 3, c = gid & 7;
    if (n >= N) return;
    int off = offs[n], dg = deg[n];
    float acc = s[(size_t)n * 8 + c];
    int i = 0;
    for (; i + 4 <= dg; i += 4) {
        int p0 = csr_src[off + i];
        int p1 = csr_src[off + i + 1];
        int p2 = csr_src[off + i + 2];
        int p3 = csr_src[off + i + 3];
        float v0 = s[(size_t)p0 * 8 + c];
        float v1 = s[(size_t)p1 * 8 + c];
        float v2 = s[(size_t)p2 * 8 + c];
        float v3 = s[(size_t)p3 * 8 + c];
        acc += (v0 + v1) + (v2 + v3);
    }
    for (; i < dg; ++i) acc += s[(size_t)csr_src[off + i] * 8 + c];
    acc *= 1.0f / (1.0f + (float)dg);
    if (c < 4) aggl[(size_t)n * 4 + c]     = acc;
    else       aggr[(size_t)n * 4 + c - 4] = acc;
}

// ---------------------------------------------------------------------------
// Fused softmax + value aggregation, single sweep (proven round-4 math).
// Changes vs round 4:
//  1. Lane-parallel weight precompute: lane l computes wexp for
//     (edge l&15, head l>>4) -> ONE aggl gather + ONE exp per lane per
//     chunk (was 16x redundant per-lane broadcast-load+exp). Consumers
//     fetch via shfl(wexp, (lane&48)+j). Denom becomes lane-local partial,
//     reduced over the 16 lanes of each head group at the end.
//  2. Binary-cascade remainder: full unmasked 16-chunks, then unmasked
//     8/4/2/1 sub-chunks per the remainder bits -> exactly dg gathers,
//     no masked/wasted iterations (round 4 wasted ~30% of gathers on
//     Poisson(16) degrees), no validity cndmasks in any inner loop.
// ---------------------------------------------------------------------------
template<int SZ>
__device__ __forceinline__ void attn_chunk(
    const int* __restrict__ csr_base, const float* __restrict__ aggl,
    float ar, int myedge, int grp, int myhead, int lane,
    const _Float16* __restrict__ xv,
    float& denom, float& o0, float& o1, float& o2, float& o3)
{
    int cs = 0;
    float wexp = 0.f;
    if (myedge < SZ) {
        cs = csr_base[myedge];
        float e = aggl[(size_t)cs * 4 + myhead] + ar;
        e = (e > 0.f) ? e : NEG_SLOPE * e;
        wexp = __expf(e);
    }
    denom += wexp;
#pragma unroll
    for (int j = 0; j < SZ; ++j) {
        int   sidx = __shfl(cs, j, 64);
        float w    = __shfl(wexp, grp + j, 64);
        half4v hv  = *(const half4v*)(xv + (size_t)sidx * 256 + lane * 4);
        o0 += w * (float)hv[0];
        o1 += w * (float)hv[1];
        o2 += w * (float)hv[2];
        o3 += w * (float)hv[3];
    }
}

__global__ __launch_bounds__(256) void attn_out(const float* __restrict__ aggl,
    const float* __restrict__ aggr, const int* __restrict__ csr_src,
    const int* __restrict__ offs, const int* __restrict__ deg,
    const _Float16* __restrict__ xv, float* __restrict__ out, int N)
{
    int wid = threadIdx.x >> 6, lane = threadIdx.x & 63;
    int n = blockIdx.x * 4 + wid;
    if (n >= N) return;
    int myhead = lane >> 4, myedge = lane & 15, grp = lane & 48;
    int off = offs[n], dg = deg[n];
    float ar = aggr[(size_t)n * 4 + myhead];

    float denom = 0.f, o0 = 0.f, o1 = 0.f, o2 = 0.f, o3 = 0.f;
    int i0 = 0;
    for (; i0 + 16 <= dg; i0 += 16)
        attn_chunk<16>(csr_src + off + i0, aggl, ar, myedge, grp, myhead, lane, xv, denom, o0, o1, o2, o3);
    int rem = dg - i0;
    if (rem & 8) {
        attn_chunk<8>(csr_src + off + i0, aggl, ar, myedge, grp, myhead, lane, xv, denom, o0, o1, o2, o3);
        i0 += 8;
    }
    if (rem & 4) {
        attn_chunk<4>(csr_src + off + i0, aggl, ar, myedge, grp, myhead, lane, xv, denom, o0, o1, o2, o3);
        i0 += 4;
    }
    if (rem & 2) {
        attn_chunk<2>(csr_src + off + i0, aggl, ar, myedge, grp, myhead, lane, xv, denom, o0, o1, o2, o3);
        i0 += 2;
    }
    if (rem & 1) {
        attn_chunk<1>(csr_src + off + i0, aggl, ar, myedge, grp, myhead, lane, xv, denom, o0, o1, o2, o3);
    }

    // Sum denom over the 16 lanes of this head group.
#pragma unroll
    for (int o = 1; o <= 8; o <<= 1) denom += __shfl_xor(denom, o, 64);
    float inv = 1.0f / fmaxf(denom, 1e-16f);
    *(float4*)(out + (size_t)n * 256 + lane * 4) = make_float4(o0 * inv, o1 * inv, o2 * inv, o3 * inv);
}

// ---------------------------------------------------------------------------
extern "C" void kernel_launch(void* const* d_in, const int* in_sizes, int n_in,
                              void* d_out, int out_size, void* d_ws, size_t ws_size,
                              hipStream_t stream)
{
    const float* x    = (const float*)d_in[0];
    const int*   src  = (const int*)d_in[1];
    const int*   dst  = (const int*)d_in[2];
    const float* Wl   = (const float*)d_in[3];
    const float* bl   = (const float*)d_in[4];
    const float* Wr   = (const float*)d_in[5];
    const float* br   = (const float*)d_in[6];
    const float* Wv   = (const float*)d_in[7];
    const float* bv   = (const float*)d_in[8];
    const float* attl = (const float*)d_in[9];
    const float* attr = (const float*)d_in[10];
    float* out = (float*)d_out;

    int N = in_sizes[0] / C_IN;
    int E = in_sizes[1];

    char* p = (char*)d_ws;
    auto alloc = [&](size_t bytes) -> void* {
        uintptr_t q = (uintptr_t)p;
        q = (q + 255) & ~(uintptr_t)255;
        p = (char*)(q + bytes);
        return (void*)q;
    };
    // Exact round-1/round-4 workspace layout (~32.8 MB, proven to fit).
    float* Ws     = (float*)alloc((size_t)C_IN * 8 * sizeof(float));
    float* bs     = (float*)alloc(8 * sizeof(float));
    float* s      = (float*)alloc((size_t)N * 8 * sizeof(float));
    float* aggl   = (float*)alloc((size_t)N * 4 * sizeof(float));
    float* aggr   = (float*)alloc((size_t)N * 4 * sizeof(float));
    int* deg      = (int*)alloc((size_t)N * sizeof(int));
    int* offs     = (int*)alloc((size_t)(N + 1) * sizeof(int));
    int* cursor   = (int*)alloc((size_t)N * sizeof(int));
    int* partials = (int*)alloc(256 * sizeof(int));
    int* pscan    = (int*)alloc(256 * sizeof(int));
    int* csr_src  = (int*)alloc((size_t)E * sizeof(int));
    _Float16* WvT = (_Float16*)alloc((size_t)C_IN * C_OUT * sizeof(_Float16));
    _Float16* xv  = (_Float16*)alloc((size_t)N * C_OUT * sizeof(_Float16));

    hipMemsetAsync(deg, 0, (size_t)N * sizeof(int), stream);
    hipMemsetAsync(cursor, 0, (size_t)N * sizeof(int), stream);

    make_eff_w<<<C_IN + 1, 256, 0, stream>>>(Wl, Wr, bl, br, attl, attr, Ws, bs);
    transpose_w<<<(C_IN * C_OUT) / 256, 256, 0, stream>>>(Wv, WvT);
    node_scores<<<768, 256, 0, stream>>>(x, Ws, bs, s, N);
    gemm_xv<<<dim3((N + 127) / 128, C_OUT / 128), 256, 0, stream>>>(x, WvT, bv, xv, N);
    deg_kernel<<<(E + 255) / 256, 256, 0, stream>>>(dst, deg, E);
    int chunk = (N + 255) / 256;
    scan_part<<<256, 256, 0, stream>>>(deg, partials, N, chunk);
    scan_partials<<<1, 256, 0, stream>>>(partials, pscan);
    scan_final<<<256, 256, 0, stream>>>(deg, pscan, offs, N, chunk);
    scatter_kernel<<<(E + 255) / 256, 256, 0, stream>>>(src, dst, offs, cursor, csr_src, E);
    agg_kernel<<<(N * 8 + 255) / 256, 256, 0, stream>>>(s, csr_src, offs, deg, aggl, aggr, N);
    attn_out<<<(N + 3) / 4, 256, 0, stream>>>(aggl, aggr, csr_src, offs, deg, xv, out, N);
}